// Round 1
// 166.520 us; speedup vs baseline: 1.1959x; 1.1959x over previous
//
#include <hip/hip_runtime.h>
#include <cstdint>
#include <cstddef>

#define BATCH 2048
#define NZ 128
#define NGEN 8
#define GRPS 32                 // samples per group (same generator)
#define MAXG 72                 // max padded groups
#define NCT 13                  // fc2 col tiles of 128 (12 full + tail 32)
#define H2_ELEMS 1792           // 32*7*8 (x padded 7->8) per sample, f16
#define WS_H1_OFF 16384                                  // h1: 72*8192 fp32
#define WS_H2_OFF (16384 + MAXG * 8192 * 4)              // 2375680
#define WS_W2T_OFF (WS_H2_OFF + BATCH * H2_ELEMS * 2)    // 9715712
#define W2T_GSTRIDE (1568 * 256)                         // fp16 elems per gen
#define NB_W2T (NGEN * 49)                               // 392
#define NB_PREP (NB_W2T + MAXG * 4)                      // 680
// packed f16x2 conv weights (pairs over input channel), per generator:
//   wpk1[g][cip16][a4][co16][c4], wpk2[g][cip8][a4][co8][c4], wpk3[g][cip4][9]
#define WS_WPK1_OFF (WS_W2T_OFF + NGEN * W2T_GSTRIDE * 2)  // 16138240 (16B aligned)
#define WS_WPK2_OFF (WS_WPK1_OFF + NGEN * 4096 * 4)
#define WS_WPK3_OFF (WS_WPK2_OFF + NGEN * 1024 * 4)

typedef unsigned int u32;
typedef unsigned short u16;
typedef _Float16 f16x8 __attribute__((ext_vector_type(8)));
typedef _Float16 f16x4 __attribute__((ext_vector_type(4)));
typedef _Float16 f16x2 __attribute__((ext_vector_type(2)));
typedef float f32x4 __attribute__((ext_vector_type(4)));

__device__ __forceinline__ float lrelu(float x) { return fmaxf(x, 0.2f * x); }
__device__ __forceinline__ u16 f16b(float f) {
    _Float16 h = (_Float16)f;
    return __builtin_bit_cast(u16, h);
}
__device__ __forceinline__ u32 pk2(float a, float b) {
    f16x2 v; v[0] = (_Float16)a; v[1] = (_Float16)b;
    return __builtin_bit_cast(u32, v);
}
// 2-wide f16 dot with f32 accumulate: v_dot2_f32_f16 (2 MACs/instr, full rate)
__device__ __forceinline__ float dot2(u32 a, u32 b, float c) {
#if __has_builtin(__builtin_amdgcn_fdot2)
    return __builtin_amdgcn_fdot2(__builtin_bit_cast(f16x2, a),
                                  __builtin_bit_cast(f16x2, b), c, false);
#else
    float d;
    asm("v_dot2_f32_f16 %0, %1, %2, %3" : "=v"(d) : "v"(a), "v"(b), "v"(c));
    return d;
#endif
}
__device__ __forceinline__ float fast_tanh(float x) {
    x = fminf(fmaxf(x, -9.f), 9.f);
    const float e = __expf(2.f * x);
    return (e - 1.f) / (e + 1.f);
}

// ---------------------------------------------------------------------------
// Kernel 1: bin samples by generator (R10-proven 1-block form).
// wsi[0] = padded total; wsi[16..] = ids grouped, groups padded to 32 w/ -1.
// ---------------------------------------------------------------------------
__global__ void bin_kernel(const int* __restrict__ g_idx, int* __restrict__ wsi) {
    __shared__ int cnt[NGEN];
    __shared__ int pbase[NGEN + 1];
    __shared__ u16 rank[BATCH];
    const int tid = threadIdx.x;
    if (tid < NGEN) cnt[tid] = 0;
    __syncthreads();
    for (int b = tid; b < BATCH; b += 256) {
        int g = g_idx[b];
        rank[b] = (u16)atomicAdd(&cnt[g], 1);
    }
    __syncthreads();
    if (tid == 0) {
        int acc = 0;
        for (int g = 0; g < NGEN; ++g) {
            pbase[g] = acc;
            acc += ((cnt[g] + GRPS - 1) / GRPS) * GRPS;
        }
        pbase[NGEN] = acc;
        wsi[0] = acc;
    }
    __syncthreads();
    const int total = pbase[NGEN];
    for (int i = tid; i < total; i += 256) wsi[16 + i] = -1;
    __syncthreads();
    for (int b = tid; b < BATCH; b += 256) {
        int g = g_idx[b];
        wsi[16 + pbase[g] + (int)rank[b]] = b;
    }
}

// ---------------------------------------------------------------------------
// Kernel 2: prep = W2 transpose (blocks 0..391) + grouped FC1 (392..679)
//           + conv-weight f16x2 packing (blocks 680..687, one per generator).
// ---------------------------------------------------------------------------
__global__ __launch_bounds__(256) void prep_kernel(
    const float* __restrict__ z, const int* __restrict__ g_idx,
    const float* __restrict__ W1, const float* __restrict__ b1,
    const float* __restrict__ W2, const int* __restrict__ wsi,
    float* __restrict__ h1g, _Float16* __restrict__ W2T,
    const float* __restrict__ cw1, const float* __restrict__ cw2,
    const float* __restrict__ cw3,
    u32* __restrict__ wpk1, u32* __restrict__ wpk2, u32* __restrict__ wpk3)
{
    __shared__ _Float16 t[32][264];   // w2t role, 16.5 KB
    __shared__ float zst[NZ][12];     // fc1 role, 6 KB
    __shared__ int sb[8];
    __shared__ int sG;

    const int tid = threadIdx.x;
    const int bx = blockIdx.x;

    if (bx >= NB_PREP) {
        // ---- conv-weight packing role: pair input channels into f16x2 ----
        const int g = bx - NB_PREP;
        const float* c1p = cw1 + g * 8192;             // [32ci][16co][4][4]
        u32* o1 = wpk1 + g * 4096;
        for (int i = tid; i < 4096; i += 256) {
            const int cip = i >> 8, a = (i >> 6) & 3, co = (i >> 2) & 15, c = i & 3;
            const float* s = c1p + cip * 512 + co * 16 + a * 4 + c;
            o1[i] = pk2(s[0], s[256]);
        }
        const float* c2p = cw2 + g * 2048;             // [16ci][8co][4][4]
        u32* o2 = wpk2 + g * 1024;
        for (int i = tid; i < 1024; i += 256) {
            const int cip = i >> 7, a = (i >> 5) & 3, co = (i >> 2) & 7, c = i & 3;
            const float* s = c2p + cip * 256 + co * 16 + a * 4 + c;
            o2[i] = pk2(s[0], s[128]);
        }
        if (tid < 36) {                                // [8ci][1co][3][3]
            const int cip = tid / 9, r = tid % 9;
            const float* s = cw3 + g * 72 + cip * 18 + r;
            wpk3[g * 36 + tid] = pk2(s[0], s[9]);
        }
        return;
    }

    if (bx < NB_W2T) {
        // ---- W2 transpose role: W2[g][k256][n1568] fp32 -> W2T[g][n][k] fp16
        const int g = bx / 49;
        const int n0 = (bx % 49) * 32;
        const float* src = W2 + (size_t)g * 256 * 1568;
        const int nl = tid & 31, kh = tid >> 5;
        #pragma unroll 8
        for (int p = 0; p < 32; ++p) {
            const int k = p * 8 + kh;
            t[nl][k] = (_Float16)src[(size_t)k * 1568 + n0 + nl];
        }
        __syncthreads();
        _Float16* dst = W2T + (size_t)g * W2T_GSTRIDE + (size_t)n0 * 256;
        const int n = tid >> 3, k0 = (tid & 7) * 32;
        #pragma unroll
        for (int j = 0; j < 4; ++j)
            *(uint4*)(dst + (size_t)n * 256 + k0 + 8 * j) = *(const uint4*)&t[n][k0 + 8 * j];
        return;
    }

    // ---- FC1 role (grouped): (group, 8-sample slice) ----
    const int bx2 = bx - NB_W2T;
    const int grp = bx2 >> 2;
    const int s0 = (bx2 & 3) * 8;
    if (grp * GRPS >= wsi[0]) return;

    if (tid == 0) sG = g_idx[wsi[16 + grp * GRPS]];
    if (tid < 8) sb[tid] = wsi[16 + grp * GRPS + s0 + tid];
    __syncthreads();
    const float* W1g = W1 + sG * (NZ * 256);
    const float* b1g = b1 + sG * 256;

    {   // stage z: 8 samples x 128 = 256 float4, one per thread
        const int s = tid >> 5, f = tid & 31;
        float4 v = make_float4(0.f, 0.f, 0.f, 0.f);
        if (sb[s] >= 0) v = *(const float4*)(z + (size_t)sb[s] * NZ + 4 * f);
        zst[4 * f + 0][s] = v.x; zst[4 * f + 1][s] = v.y;
        zst[4 * f + 2][s] = v.z; zst[4 * f + 3][s] = v.w;
    }
    __syncthreads();

    const int c = tid;
    float acc[8];
    #pragma unroll
    for (int s = 0; s < 8; ++s) acc[s] = 0.f;
    const float* wp = W1g + c;
    #pragma unroll 4
    for (int k = 0; k < NZ; ++k) {
        const float w = wp[k * 256];
        float av[8];
        *(float4*)&av[0] = *(const float4*)&zst[k][0];
        *(float4*)&av[4] = *(const float4*)&zst[k][4];
        #pragma unroll
        for (int s = 0; s < 8; ++s) acc[s] += av[s] * w;
    }
    const float bv = b1g[c];
    float* hp = h1g + (size_t)grp * 8192 + (size_t)s0 * 256 + c;
    #pragma unroll
    for (int s = 0; s < 8; ++s) hp[s * 256] = lrelu(acc[s] + bv);
}

// ---------------------------------------------------------------------------
// Kernel 3: FC2 via fp16 MFMA 16x16x32 — conflict-free staging + split-pass.
// (unchanged except h2g now stores f16 bits instead of bf16: better precision,
//  and conv stage can repack without conversion.)
// ---------------------------------------------------------------------------
__global__ __launch_bounds__(256) void fc2_kernel(
    const int* __restrict__ g_idx,
    const _Float16* __restrict__ W2T, const float* __restrict__ b2,
    const int* __restrict__ wsi, const float* __restrict__ h1g,
    u16* __restrict__ h2g)
{
    __shared__ _Float16 afrag[2 * 2 * 8 * 64 * 8];   // [mt*2+h][kq][lane][8], 32 KB
    __shared__ int sb[GRPS];
    __shared__ int sG;

    const int tid = threadIdx.x;
    const int grp = blockIdx.x / NCT;
    const int tile = blockIdx.x % NCT;
    if (grp * GRPS >= wsi[0]) return;

    if (tid == 0) sG = g_idx[wsi[16 + grp * GRPS]];
    if (tid < GRPS) sb[tid] = wsi[16 + grp * GRPS + tid];
    __syncthreads();
    const _Float16* W2Tg = W2T + (size_t)sG * W2T_GSTRIDE;
    const float* b2g = b2 + sG * 1568;

    // ---- stage A fragments (hi/lo split), conflict-free stores ----
    {
        const float4* h1p4 = (const float4*)(h1g + (size_t)grp * 8192);
        #pragma unroll
        for (int i = 0; i < 8; ++i) {
            const int u = tid + 256 * i;
            const int j4 = u & 1;                  // j base = 4*j4
            const int lane = (u >> 1) & 63;
            const int kq = (u >> 7) & 7;
            const int mt = (u >> 10) & 1;
            const int s = mt * 16 + (lane & 15);
            const float4 v = h1p4[s * 64 + kq * 8 + ((lane >> 4) << 1) + j4];
            const float vv[4] = {v.x, v.y, v.z, v.w};
            f16x4 hi, lo;
            #pragma unroll
            for (int e = 0; e < 4; ++e) {
                hi[e] = (_Float16)vv[e];
                lo[e] = (_Float16)(vv[e] - (float)hi[e]);
            }
            const int bh = (((mt * 2 + 0) * 8 + kq) * 64 + lane) * 8 + 4 * j4;
            const int bl = (((mt * 2 + 1) * 8 + kq) * 64 + lane) * 8 + 4 * j4;
            *(f16x4*)&afrag[bh] = hi;   // addr = base + 8*tid bytes: conflict-free
            *(f16x4*)&afrag[bl] = lo;
        }
    }
    __syncthreads();

    const int wave = tid >> 6;
    const int lane = tid & 63;
    const int q = lane >> 4;
    const int nl = lane & 15;
    const int nb0 = tile * 128 + 2 * wave * 16;
    if (nb0 >= 1568) return;

    #pragma unroll
    for (int nt = 0; nt < 2; ++nt) {
        const int nb = nb0 + nt * 16;
        if (nb >= 1568) break;
        const int n = nb + nl;
        const _Float16* bp = W2Tg + (size_t)n * 256 + q * 8;
        f32x4 accA = {0.f, 0.f, 0.f, 0.f}, accB = accA;
        #pragma unroll
        for (int kq = 0; kq < 8; ++kq) {
            const f16x8 b = *(const f16x8*)(bp + kq * 32);
            const f16x8 a0h = *(const f16x8*)&afrag[((0 * 8 + kq) * 64 + lane) * 8];
            const f16x8 a0l = *(const f16x8*)&afrag[((1 * 8 + kq) * 64 + lane) * 8];
            const f16x8 a1h = *(const f16x8*)&afrag[((2 * 8 + kq) * 64 + lane) * 8];
            const f16x8 a1l = *(const f16x8*)&afrag[((3 * 8 + kq) * 64 + lane) * 8];
            accA = __builtin_amdgcn_mfma_f32_16x16x32_f16(a0h, b, accA, 0, 0, 0);
            accA = __builtin_amdgcn_mfma_f32_16x16x32_f16(a0l, b, accA, 0, 0, 0);
            accB = __builtin_amdgcn_mfma_f32_16x16x32_f16(a1h, b, accB, 0, 0, 0);
            accB = __builtin_amdgcn_mfma_f32_16x16x32_f16(a1l, b, accB, 0, 0, 0);
        }
        // epilogue for this n-tile
        const float bias = b2g[n];
        const int ci = n / 49, rm = n % 49;
        const int off = ci * 56 + (rm / 7) * 8 + (rm % 7);
        #pragma unroll
        for (int mt = 0; mt < 2; ++mt) {
            const f32x4 a = (mt == 0) ? accA : accB;
            #pragma unroll
            for (int reg = 0; reg < 4; ++reg) {
                const int s = mt * 16 + q * 4 + reg;
                const int bb = sb[s];
                if (bb >= 0)
                    h2g[(size_t)bb * H2_ELEMS + off] = f16b(lrelu(a[reg] + bias));
            }
        }
    }
}

// ---------------------------------------------------------------------------
// conv2 half-pass, f16x2-pair form: contraction over ci-pairs via v_dot2.
// c1s rows padded to 20 u32 (80 B) to keep iy-stride bank pattern <=2-way.
// ---------------------------------------------------------------------------
template <int H>
__device__ __forceinline__ void conv2p_half(
    const u32 (*c1s)[14][20], u16* dst,
    const u32* __restrict__ w2g, const float bv, const int co, const int y)
{
    float acc[14];
    #pragma unroll
    for (int xx = 0; xx < 14; ++xx) acc[xx] = bv;
    const int a0 = (y + 1) & 1;
    for (int aa = 0; aa < 2; ++aa) {
        const int a = a0 + 2 * aa;
        const int iy = (y + 1 - a) >> 1;
        if ((unsigned)iy < 14u) {
            #pragma unroll 2
            for (int cip = 0; cip < 8; ++cip) {
                u32 rr[10];                         // H0: ix 0..7; H1: ix 4..13
                if (H == 0) {
                    *(uint4*)&rr[0] = *(const uint4*)&c1s[cip][iy][0];
                    *(uint4*)&rr[4] = *(const uint4*)&c1s[cip][iy][4];
                } else {
                    *(uint4*)&rr[0] = *(const uint4*)&c1s[cip][iy][4];
                    *(uint4*)&rr[4] = *(const uint4*)&c1s[cip][iy][8];
                    *(uint2*)&rr[8] = *(const uint2*)&c1s[cip][iy][12];
                }
                const uint4 wq = *(const uint4*)(w2g + ((cip * 4 + a) * 8 + co) * 4);
                const u32 wv[4] = {wq.x, wq.y, wq.z, wq.w};
                #pragma unroll
                for (int xx = 0; xx < 14; ++xx) {
                    const int x = 14 * H + xx;
                    const int c0v = (x + 1) & 1;
                    const int ix0 = (x + 1 - c0v) >> 1;
                    const int li = ix0 - 4 * H;
                    if (ix0 < 14) acc[xx] = dot2(rr[li],     wv[c0v],     acc[xx]);
                    if (ix0 >= 1) acc[xx] = dot2(rr[li - 1], wv[c0v + 2], acc[xx]);
                }
            }
        }
    }
    #pragma unroll
    for (int xx = 0; xx < 14; ++xx) dst[2 * (14 * H + xx)] = f16b(lrelu(acc[xx]));
}

// ---------------------------------------------------------------------------
// Kernel 4: all three transposed convs, ONE sample per block.
// f16x2 channel-pair form: every MAC is v_dot2_f32_f16 (2 MACs/instr, f32 acc)
// -> ~half the FMA-class instructions of the fp32 version, half the LDS bytes.
// LDS: c1s 8.75 KB | h2s 3.5 KB (dead after conv1) aliased by c2s 14.4 KB
// = 23.2 KB -> 6 blocks/CU (was 5 at 31.7 KB).
// ---------------------------------------------------------------------------
__global__ __launch_bounds__(256, 6) void conv_kernel(
    const int* __restrict__ g_idx,
    const u32* __restrict__ wpk1, const float* __restrict__ cb1,
    const u32* __restrict__ wpk2, const float* __restrict__ cb2,
    const u32* __restrict__ wpk3, const float* __restrict__ cb3,
    const u16* __restrict__ h2g, float* __restrict__ out)
{
    __shared__ __align__(16) char smem[8960 + 14784];
    u32 (*c1s)[14][20] = (u32 (*)[14][20])smem;              // [8cip][14][20] 8960 B
    u32 (*h2s)[7][8]   = (u32 (*)[7][8])(smem + 8960);       // [16cip][7][8] 3584 B
    u32 (*c2s)[28][33] = (u32 (*)[28][33])(smem + 8960);     // [4cip][28][33] aliases h2s
    __shared__ u32 w3s[36];

    const int tid = threadIdx.x;
    const int b = blockIdx.x;
    const int g = g_idx[b];
    const u32* w1g = wpk1 + g * 4096;
    const u32* w2g = wpk2 + g * 1024;
    const float* cb1g = cb1 + g * 16;
    const float* cb2g = cb2 + g * 8;
    const float  cb3v = cb3[g];

    // stage h2 (f16 bits straight from fc2) into ci-paired layout
    if (tid < 224) {
        const uint4 qv = ((const uint4*)(h2g + (size_t)b * H2_ELEMS))[tid];
        const int ci = tid / 7, yq = tid % 7;
        u16* dst = (u16*)&h2s[ci >> 1][yq][0] + (ci & 1);
        const u32 w[4] = {qv.x, qv.y, qv.z, qv.w};
        #pragma unroll
        for (int j = 0; j < 4; ++j) {
            dst[4 * j]     = (u16)(w[j] & 0xffffu);
            dst[4 * j + 2] = (u16)(w[j] >> 16);
        }
    }
    if (tid < 36) w3s[tid] = wpk3[g * 36 + tid];
    __syncthreads();

    // conv1: [32,7,7] -> [16,14,14], k=4, s=2, ci-pairs via dot2
    if (tid < 224) {
        const int co = tid / 14, y = tid % 14;
        const float bv = cb1g[co];
        float acc[14];
        #pragma unroll
        for (int x = 0; x < 14; ++x) acc[x] = bv;
        const int a0 = (y + 1) & 1;
        for (int aa = 0; aa < 2; ++aa) {
            const int a = a0 + 2 * aa;
            const int iy = (y + 1 - a) >> 1;
            if ((unsigned)iy < 7u) {
                #pragma unroll 2
                for (int cip = 0; cip < 16; ++cip) {
                    u32 rr[8];
                    *(uint4*)&rr[0] = *(const uint4*)&h2s[cip][iy][0];
                    *(uint4*)&rr[4] = *(const uint4*)&h2s[cip][iy][4];
                    const uint4 wq = *(const uint4*)(w1g + ((cip * 4 + a) * 16 + co) * 4);
                    const u32 wv[4] = {wq.x, wq.y, wq.z, wq.w};
                    #pragma unroll
                    for (int x = 0; x < 14; ++x) {
                        const int c0v = (x + 1) & 1;
                        const int ix0 = (x + 1 - c0v) >> 1;
                        if (ix0 < 7)  acc[x] = dot2(rr[ix0],     wv[c0v],     acc[x]);
                        if (ix0 >= 1) acc[x] = dot2(rr[ix0 - 1], wv[c0v + 2], acc[x]);
                    }
                }
            }
        }
        u16* dst = (u16*)&c1s[co >> 1][y][0] + (co & 1);
        #pragma unroll
        for (int x = 0; x < 14; ++x) dst[2 * x] = f16b(lrelu(acc[x]));
    }
    __syncthreads();   // h2s dead; c2s may be written

    // conv2: [16,14,14] -> [8,28,28]
    if (tid < 224) {
        const int co = tid / 28, y = tid % 28;
        const float bv = cb2g[co];
        u16* dst = (u16*)&c2s[co >> 1][y][0] + (co & 1);
        conv2p_half<0>(c1s, dst, w2g, bv, co, y);
        conv2p_half<1>(c1s, dst, w2g, bv, co, y);
    }
    __syncthreads();

    // conv3: [8,28,28] -> [1,28,28], k=3 s=1, ci-pairs via dot2
    if (tid < 196) {
        const int y = tid / 7, qq = tid % 7;
        const int xb = qq * 4;
        float acc[4] = {cb3v, cb3v, cb3v, cb3v};
        #pragma unroll 2
        for (int cip = 0; cip < 4; ++cip) {
            u32 wp[9];
            #pragma unroll
            for (int j = 0; j < 9; ++j) wp[j] = w3s[cip * 9 + j];
            #pragma unroll
            for (int a = 0; a < 3; ++a) {
                const int iy = y + 1 - a;
                if ((unsigned)iy < 28u) {
                    u32 rr[6];
                    #pragma unroll
                    for (int j = 0; j < 6; ++j) {
                        const int ix = xb - 1 + j;
                        rr[j] = ((unsigned)ix < 28u) ? c2s[cip][iy][ix] : 0u;
                    }
                    #pragma unroll
                    for (int xx = 0; xx < 4; ++xx)
                        #pragma unroll
                        for (int c = 0; c < 3; ++c)
                            acc[xx] = dot2(rr[xx + 2 - c], wp[a * 3 + c], acc[xx]);
                }
            }
        }
        float* op = out + (size_t)b * 784 + y * 28 + xb;
        #pragma unroll
        for (int xx = 0; xx < 4; ++xx) op[xx] = fast_tanh(acc[xx]);
    }
}

extern "C" void kernel_launch(void* const* d_in, const int* in_sizes, int n_in,
                              void* d_out, int out_size, void* d_ws, size_t ws_size,
                              hipStream_t stream) {
    const float* z   = (const float*)d_in[0];
    const int*   gi  = (const int*)d_in[1];
    const float* W1  = (const float*)d_in[2];
    const float* b1  = (const float*)d_in[3];
    const float* W2  = (const float*)d_in[4];
    const float* b2  = (const float*)d_in[5];
    const float* cw1 = (const float*)d_in[6];
    const float* cb1 = (const float*)d_in[7];
    const float* cw2 = (const float*)d_in[8];
    const float* cb2 = (const float*)d_in[9];
    const float* cw3 = (const float*)d_in[10];
    const float* cb3 = (const float*)d_in[11];
    int*      wsi = (int*)d_ws;
    float*    h1g = (float*)((char*)d_ws + WS_H1_OFF);
    u16*      h2g = (u16*)((char*)d_ws + WS_H2_OFF);
    _Float16* w2t = (_Float16*)((char*)d_ws + WS_W2T_OFF);
    u32*      wpk1 = (u32*)((char*)d_ws + WS_WPK1_OFF);
    u32*      wpk2 = (u32*)((char*)d_ws + WS_WPK2_OFF);
    u32*      wpk3 = (u32*)((char*)d_ws + WS_WPK3_OFF);

    bin_kernel<<<1, 256, 0, stream>>>(gi, wsi);
    prep_kernel<<<NB_PREP + NGEN, 256, 0, stream>>>(z, gi, W1, b1, W2, wsi, h1g, w2t,
                                                    cw1, cw2, cw3, wpk1, wpk2, wpk3);
    fc2_kernel<<<MAXG * NCT, 256, 0, stream>>>(gi, w2t, b2, wsi, h1g, h2g);
    conv_kernel<<<BATCH, 256, 0, stream>>>(gi, wpk1, cb1, wpk2, cb2, wpk3, cb3,
                                           h2g, (float*)d_out);
}

// Round 2
// 166.411 us; speedup vs baseline: 1.1966x; 1.0007x over previous
//
#include <hip/hip_runtime.h>
#include <cstdint>
#include <cstddef>

#define BATCH 2048
#define NZ 128
#define NGEN 8
#define GRPS 32                 // samples per group (same generator)
#define MAXG 72                 // max padded groups
#define NCT 13                  // fc2 col tiles of 128 (12 full + tail 32)
#define H2_ELEMS 1792           // 32*7*8 (x padded 7->8) per sample, f16
#define WS_H1_OFF 16384                                  // h1: 72*8192 fp32
#define WS_H2_OFF (16384 + MAXG * 8192 * 4)              // 2375680
#define WS_W2T_OFF (WS_H2_OFF + BATCH * H2_ELEMS * 2)    // 9715712
#define W2T_GSTRIDE (1568 * 256)                         // fp16 elems per gen
#define NB_W2T (NGEN * 49)                               // 392
#define NB_PREP (NB_W2T + MAXG * 4)                      // 680
// packed f16x2 conv weights (pairs over input channel), per generator:
//   wpk1[g][cip16][a4][co16][c4], wpk2[g][cip8][a4][co8][c4], wpk3[g][cip4][9]
#define WS_WPK1_OFF (WS_W2T_OFF + NGEN * W2T_GSTRIDE * 2)  // 16138240 (16B aligned)
#define WS_WPK2_OFF (WS_WPK1_OFF + NGEN * 4096 * 4)
#define WS_WPK3_OFF (WS_WPK2_OFF + NGEN * 1024 * 4)

typedef unsigned int u32;
typedef unsigned short u16;
typedef unsigned long long u64;
typedef _Float16 f16x8 __attribute__((ext_vector_type(8)));
typedef _Float16 f16x4 __attribute__((ext_vector_type(4)));
typedef _Float16 f16x2 __attribute__((ext_vector_type(2)));
typedef float f32x4 __attribute__((ext_vector_type(4)));

__device__ __forceinline__ float lrelu(float x) { return fmaxf(x, 0.2f * x); }
__device__ __forceinline__ u16 f16b(float f) {
    _Float16 h = (_Float16)f;
    return __builtin_bit_cast(u16, h);
}
__device__ __forceinline__ u32 pk2(float a, float b) {
    f16x2 v; v[0] = (_Float16)a; v[1] = (_Float16)b;
    return __builtin_bit_cast(u32, v);
}
// 2-wide f16 dot with f32 accumulate: v_dot2_f32_f16 (2 MACs/instr, full rate)
__device__ __forceinline__ float dot2(u32 a, u32 b, float c) {
#if __has_builtin(__builtin_amdgcn_fdot2)
    return __builtin_amdgcn_fdot2(__builtin_bit_cast(f16x2, a),
                                  __builtin_bit_cast(f16x2, b), c, false);
#else
    float d;
    asm("v_dot2_f32_f16 %0, %1, %2, %3" : "=v"(d) : "v"(a), "v"(b), "v"(c));
    return d;
#endif
}
__device__ __forceinline__ float fast_tanh(float x) {
    x = fminf(fmaxf(x, -9.f), 9.f);
    const float e = __expf(2.f * x);
    return (e - 1.f) / (e + 1.f);
}

// ---------------------------------------------------------------------------
// Kernel 1: bin samples by generator — ballot-rank form (no LDS atomics).
// Rank within a generator need not be stable (output gather is by sample id),
// so per-wave ballot ranks + per-wave base offsets replace 2048 serialized
// atomics to 8 addresses.
// wsi[0] = padded total; wsi[16..] = ids grouped, groups padded to 32 w/ -1.
// ---------------------------------------------------------------------------
__global__ void bin_kernel(const int* __restrict__ g_idx, int* __restrict__ wsi) {
    __shared__ int wcnt[4][NGEN];      // per-wave per-gen counts
    __shared__ int wboff[4][NGEN];     // per-wave base offset inside gen region
    __shared__ int pbase[NGEN + 1];
    __shared__ u16 rank[BATCH];        // wave-local rank within gen
    const int tid = threadIdx.x;
    const int w = tid >> 6, lane = tid & 63;
    if (tid < 4 * NGEN) wcnt[tid >> 3][tid & 7] = 0;
    __syncthreads();
    const u64 lt = ((u64)1 << lane) - 1;   // lane=63: low 63 bits set (1<<63 ok)
    #pragma unroll
    for (int r = 0; r < 8; ++r) {
        const int b = r * 256 + tid;
        const int gg = g_idx[b];
        u64 m[NGEN];
        #pragma unroll
        for (int k = 0; k < NGEN; ++k) m[k] = __ballot(gg == k);
        rank[b] = (u16)((int)__popcll(m[gg] & lt) + wcnt[w][gg]);
        if (lane < NGEN) wcnt[w][lane] += (int)__popcll(m[lane]);
    }
    __syncthreads();
    if (tid == 0) {
        int acc = 0;
        for (int g = 0; g < NGEN; ++g) {
            pbase[g] = acc;
            const int tot = wcnt[0][g] + wcnt[1][g] + wcnt[2][g] + wcnt[3][g];
            acc += ((tot + GRPS - 1) / GRPS) * GRPS;
        }
        pbase[NGEN] = acc;
        wsi[0] = acc;
    }
    __syncthreads();
    if (tid < 32) {
        const int ww = tid >> 3, g = tid & 7;
        int off = pbase[g];
        for (int w2 = 0; w2 < ww; ++w2) off += wcnt[w2][g];
        wboff[ww][g] = off;
    }
    const int total = pbase[NGEN];
    for (int i = tid; i < total; i += 256) wsi[16 + i] = -1;
    __syncthreads();
    #pragma unroll
    for (int r = 0; r < 8; ++r) {
        const int b = r * 256 + tid;
        const int gg = g_idx[b];
        wsi[16 + wboff[w][gg] + (int)rank[b]] = b;
    }
}

// ---------------------------------------------------------------------------
// Kernel 2: prep = W2 transpose (blocks 0..391) + grouped FC1 (392..679)
//           + conv-weight f16x2 packing (blocks 680..687, one per generator).
// ---------------------------------------------------------------------------
__global__ __launch_bounds__(256) void prep_kernel(
    const float* __restrict__ z, const int* __restrict__ g_idx,
    const float* __restrict__ W1, const float* __restrict__ b1,
    const float* __restrict__ W2, const int* __restrict__ wsi,
    float* __restrict__ h1g, _Float16* __restrict__ W2T,
    const float* __restrict__ cw1, const float* __restrict__ cw2,
    const float* __restrict__ cw3,
    u32* __restrict__ wpk1, u32* __restrict__ wpk2, u32* __restrict__ wpk3)
{
    __shared__ _Float16 t[32][264];   // w2t role, 16.5 KB
    __shared__ float zst[NZ][12];     // fc1 role, 6 KB
    __shared__ int sb[8];
    __shared__ int sG;

    const int tid = threadIdx.x;
    const int bx = blockIdx.x;

    if (bx >= NB_PREP) {
        // ---- conv-weight packing role: pair input channels into f16x2 ----
        const int g = bx - NB_PREP;
        const float* c1p = cw1 + g * 8192;             // [32ci][16co][4][4]
        u32* o1 = wpk1 + g * 4096;
        for (int i = tid; i < 4096; i += 256) {
            const int cip = i >> 8, a = (i >> 6) & 3, co = (i >> 2) & 15, c = i & 3;
            const float* s = c1p + cip * 512 + co * 16 + a * 4 + c;
            o1[i] = pk2(s[0], s[256]);
        }
        const float* c2p = cw2 + g * 2048;             // [16ci][8co][4][4]
        u32* o2 = wpk2 + g * 1024;
        for (int i = tid; i < 1024; i += 256) {
            const int cip = i >> 7, a = (i >> 5) & 3, co = (i >> 2) & 7, c = i & 3;
            const float* s = c2p + cip * 256 + co * 16 + a * 4 + c;
            o2[i] = pk2(s[0], s[128]);
        }
        if (tid < 36) {                                // [8ci][1co][3][3]
            const int cip = tid / 9, r = tid % 9;
            const float* s = cw3 + g * 72 + cip * 18 + r;
            wpk3[g * 36 + tid] = pk2(s[0], s[9]);
        }
        return;
    }

    if (bx < NB_W2T) {
        // ---- W2 transpose role: W2[g][k256][n1568] fp32 -> W2T[g][n][k] fp16
        const int g = bx / 49;
        const int n0 = (bx % 49) * 32;
        const float* src = W2 + (size_t)g * 256 * 1568;
        const int nl = tid & 31, kh = tid >> 5;
        #pragma unroll 8
        for (int p = 0; p < 32; ++p) {
            const int k = p * 8 + kh;
            t[nl][k] = (_Float16)src[(size_t)k * 1568 + n0 + nl];
        }
        __syncthreads();
        _Float16* dst = W2T + (size_t)g * W2T_GSTRIDE + (size_t)n0 * 256;
        const int n = tid >> 3, k0 = (tid & 7) * 32;
        #pragma unroll
        for (int j = 0; j < 4; ++j)
            *(uint4*)(dst + (size_t)n * 256 + k0 + 8 * j) = *(const uint4*)&t[n][k0 + 8 * j];
        return;
    }

    // ---- FC1 role (grouped): (group, 8-sample slice) ----
    const int bx2 = bx - NB_W2T;
    const int grp = bx2 >> 2;
    const int s0 = (bx2 & 3) * 8;
    if (grp * GRPS >= wsi[0]) return;

    if (tid == 0) sG = g_idx[wsi[16 + grp * GRPS]];
    if (tid < 8) sb[tid] = wsi[16 + grp * GRPS + s0 + tid];
    __syncthreads();
    const float* W1g = W1 + sG * (NZ * 256);
    const float* b1g = b1 + sG * 256;

    {   // stage z: 8 samples x 128 = 256 float4, one per thread
        const int s = tid >> 5, f = tid & 31;
        float4 v = make_float4(0.f, 0.f, 0.f, 0.f);
        if (sb[s] >= 0) v = *(const float4*)(z + (size_t)sb[s] * NZ + 4 * f);
        zst[4 * f + 0][s] = v.x; zst[4 * f + 1][s] = v.y;
        zst[4 * f + 2][s] = v.z; zst[4 * f + 3][s] = v.w;
    }
    __syncthreads();

    const int c = tid;
    float acc[8];
    #pragma unroll
    for (int s = 0; s < 8; ++s) acc[s] = 0.f;
    const float* wp = W1g + c;
    #pragma unroll 4
    for (int k = 0; k < NZ; ++k) {
        const float w = wp[k * 256];
        float av[8];
        *(float4*)&av[0] = *(const float4*)&zst[k][0];
        *(float4*)&av[4] = *(const float4*)&zst[k][4];
        #pragma unroll
        for (int s = 0; s < 8; ++s) acc[s] += av[s] * w;
    }
    const float bv = b1g[c];
    float* hp = h1g + (size_t)grp * 8192 + (size_t)s0 * 256 + c;
    #pragma unroll
    for (int s = 0; s < 8; ++s) hp[s * 256] = lrelu(acc[s] + bv);
}

// ---------------------------------------------------------------------------
// Kernel 3: FC2 via fp16 MFMA 16x16x32 — single-f16 A (lo-term dropped: B is
// already single-f16, so A's extra precision was not the dominant error).
// afrag 16 KB (was 32) -> 8 blocks/CU; half the MFMA + staging work.
// Staging map: u = tid + 256*i; j4=u&1, lane=(u>>1)&63, kq=(u>>7)&7,
// mt=(u>>10)&1; LDS store addr = base + 8*u bytes -> conflict-free.
// C/D layout: col(n)=lane&15, row(m)=(lane>>4)*4+reg [m89].
// ---------------------------------------------------------------------------
__global__ __launch_bounds__(256) void fc2_kernel(
    const int* __restrict__ g_idx,
    const _Float16* __restrict__ W2T, const float* __restrict__ b2,
    const int* __restrict__ wsi, const float* __restrict__ h1g,
    u16* __restrict__ h2g)
{
    __shared__ _Float16 afrag[2 * 8 * 64 * 8];   // [mt][kq][lane][8], 16 KB
    __shared__ int sb[GRPS];
    __shared__ int sG;

    const int tid = threadIdx.x;
    const int grp = blockIdx.x / NCT;
    const int tile = blockIdx.x % NCT;
    if (grp * GRPS >= wsi[0]) return;

    if (tid == 0) sG = g_idx[wsi[16 + grp * GRPS]];
    if (tid < GRPS) sb[tid] = wsi[16 + grp * GRPS + tid];
    __syncthreads();
    const _Float16* W2Tg = W2T + (size_t)sG * W2T_GSTRIDE;
    const float* b2g = b2 + sG * 1568;

    // ---- stage A fragments (single f16), conflict-free stores ----
    {
        const float4* h1p4 = (const float4*)(h1g + (size_t)grp * 8192);
        #pragma unroll
        for (int i = 0; i < 8; ++i) {
            const int u = tid + 256 * i;
            const int j4 = u & 1;                  // j base = 4*j4
            const int ln = (u >> 1) & 63;
            const int kq = (u >> 7) & 7;
            const int mt = (u >> 10) & 1;
            const int s = mt * 16 + (ln & 15);
            const float4 v = h1p4[s * 64 + kq * 8 + ((ln >> 4) << 1) + j4];
            f16x4 hi;
            hi[0] = (_Float16)v.x; hi[1] = (_Float16)v.y;
            hi[2] = (_Float16)v.z; hi[3] = (_Float16)v.w;
            const int bh = ((mt * 8 + kq) * 64 + ln) * 8 + 4 * j4;
            *(f16x4*)&afrag[bh] = hi;   // addr = base + 8*u bytes: conflict-free
        }
    }
    __syncthreads();

    const int wave = tid >> 6;
    const int lane = tid & 63;
    const int q = lane >> 4;
    const int nl = lane & 15;
    const int nb0 = tile * 128 + 2 * wave * 16;
    if (nb0 >= 1568) return;

    #pragma unroll
    for (int nt = 0; nt < 2; ++nt) {
        const int nb = nb0 + nt * 16;
        if (nb >= 1568) break;
        const int n = nb + nl;
        const _Float16* bp = W2Tg + (size_t)n * 256 + q * 8;
        f32x4 accA = {0.f, 0.f, 0.f, 0.f}, accB = accA;
        #pragma unroll
        for (int kq = 0; kq < 8; ++kq) {
            const f16x8 b = *(const f16x8*)(bp + kq * 32);
            const f16x8 a0 = *(const f16x8*)&afrag[((0 * 8 + kq) * 64 + lane) * 8];
            const f16x8 a1 = *(const f16x8*)&afrag[((1 * 8 + kq) * 64 + lane) * 8];
            accA = __builtin_amdgcn_mfma_f32_16x16x32_f16(a0, b, accA, 0, 0, 0);
            accB = __builtin_amdgcn_mfma_f32_16x16x32_f16(a1, b, accB, 0, 0, 0);
        }
        // epilogue for this n-tile
        const float bias = b2g[n];
        const int ci = n / 49, rm = n % 49;
        const int off = ci * 56 + (rm / 7) * 8 + (rm % 7);
        #pragma unroll
        for (int mt = 0; mt < 2; ++mt) {
            const f32x4 a = (mt == 0) ? accA : accB;
            #pragma unroll
            for (int reg = 0; reg < 4; ++reg) {
                const int s = mt * 16 + q * 4 + reg;
                const int bb = sb[s];
                if (bb >= 0)
                    h2g[(size_t)bb * H2_ELEMS + off] = f16b(lrelu(a[reg] + bias));
            }
        }
    }
}

// ---------------------------------------------------------------------------
// conv2 half-pass, f16x2-pair form: contraction over ci-pairs via v_dot2.
// c1s rows padded to 20 u32 (80 B) to keep iy-stride bank pattern <=2-way.
// ---------------------------------------------------------------------------
template <int H>
__device__ __forceinline__ void conv2p_half(
    const u32 (*c1s)[14][20], u16* dst,
    const u32* __restrict__ w2g, const float bv, const int co, const int y)
{
    float acc[14];
    #pragma unroll
    for (int xx = 0; xx < 14; ++xx) acc[xx] = bv;
    const int a0 = (y + 1) & 1;
    for (int aa = 0; aa < 2; ++aa) {
        const int a = a0 + 2 * aa;
        const int iy = (y + 1 - a) >> 1;
        if ((unsigned)iy < 14u) {
            #pragma unroll 2
            for (int cip = 0; cip < 8; ++cip) {
                u32 rr[10];                         // H0: ix 0..7; H1: ix 4..13
                if (H == 0) {
                    *(uint4*)&rr[0] = *(const uint4*)&c1s[cip][iy][0];
                    *(uint4*)&rr[4] = *(const uint4*)&c1s[cip][iy][4];
                } else {
                    *(uint4*)&rr[0] = *(const uint4*)&c1s[cip][iy][4];
                    *(uint4*)&rr[4] = *(const uint4*)&c1s[cip][iy][8];
                    *(uint2*)&rr[8] = *(const uint2*)&c1s[cip][iy][12];
                }
                const uint4 wq = *(const uint4*)(w2g + ((cip * 4 + a) * 8 + co) * 4);
                const u32 wv[4] = {wq.x, wq.y, wq.z, wq.w};
                #pragma unroll
                for (int xx = 0; xx < 14; ++xx) {
                    const int x = 14 * H + xx;
                    const int c0v = (x + 1) & 1;
                    const int ix0 = (x + 1 - c0v) >> 1;
                    const int li = ix0 - 4 * H;
                    if (ix0 < 14) acc[xx] = dot2(rr[li],     wv[c0v],     acc[xx]);
                    if (ix0 >= 1) acc[xx] = dot2(rr[li - 1], wv[c0v + 2], acc[xx]);
                }
            }
        }
    }
    #pragma unroll
    for (int xx = 0; xx < 14; ++xx) dst[2 * (14 * H + xx)] = f16b(lrelu(acc[xx]));
}

// ---------------------------------------------------------------------------
// Kernel 4: all three transposed convs, ONE sample per block.
// f16x2 channel-pair form: every MAC is v_dot2_f32_f16 (2 MACs/instr, f32 acc).
// LDS: c1s 8.75 KB | h2s 3.5 KB (dead after conv1) aliased by c2s 12.7 KB
// (stride 29, odd -> bank spread kept) = ~22.1 KB -> 7 blocks/CU (was 6).
// ---------------------------------------------------------------------------
__global__ __launch_bounds__(256, 7) void conv_kernel(
    const int* __restrict__ g_idx,
    const u32* __restrict__ wpk1, const float* __restrict__ cb1,
    const u32* __restrict__ wpk2, const float* __restrict__ cb2,
    const u32* __restrict__ wpk3, const float* __restrict__ cb3,
    const u16* __restrict__ h2g, float* __restrict__ out)
{
    __shared__ __align__(16) char smem[8960 + 12992];
    u32 (*c1s)[14][20] = (u32 (*)[14][20])smem;              // [8cip][14][20] 8960 B
    u32 (*h2s)[7][8]   = (u32 (*)[7][8])(smem + 8960);       // [16cip][7][8] 3584 B
    u32 (*c2s)[28][29] = (u32 (*)[28][29])(smem + 8960);     // [4cip][28][29] aliases h2s
    __shared__ u32 w3s[36];

    const int tid = threadIdx.x;
    const int b = blockIdx.x;
    const int g = g_idx[b];
    const u32* w1g = wpk1 + g * 4096;
    const u32* w2g = wpk2 + g * 1024;
    const float* cb1g = cb1 + g * 16;
    const float* cb2g = cb2 + g * 8;
    const float  cb3v = cb3[g];

    // stage h2 (f16 bits straight from fc2) into ci-paired layout
    if (tid < 224) {
        const uint4 qv = ((const uint4*)(h2g + (size_t)b * H2_ELEMS))[tid];
        const int ci = tid / 7, yq = tid % 7;
        u16* dst = (u16*)&h2s[ci >> 1][yq][0] + (ci & 1);
        const u32 w[4] = {qv.x, qv.y, qv.z, qv.w};
        #pragma unroll
        for (int j = 0; j < 4; ++j) {
            dst[4 * j]     = (u16)(w[j] & 0xffffu);
            dst[4 * j + 2] = (u16)(w[j] >> 16);
        }
    }
    if (tid < 36) w3s[tid] = wpk3[g * 36 + tid];
    __syncthreads();

    // conv1: [32,7,7] -> [16,14,14], k=4, s=2, ci-pairs via dot2
    if (tid < 224) {
        const int co = tid / 14, y = tid % 14;
        const float bv = cb1g[co];
        float acc[14];
        #pragma unroll
        for (int x = 0; x < 14; ++x) acc[x] = bv;
        const int a0 = (y + 1) & 1;
        for (int aa = 0; aa < 2; ++aa) {
            const int a = a0 + 2 * aa;
            const int iy = (y + 1 - a) >> 1;
            if ((unsigned)iy < 7u) {
                #pragma unroll 2
                for (int cip = 0; cip < 16; ++cip) {
                    u32 rr[8];
                    *(uint4*)&rr[0] = *(const uint4*)&h2s[cip][iy][0];
                    *(uint4*)&rr[4] = *(const uint4*)&h2s[cip][iy][4];
                    const uint4 wq = *(const uint4*)(w1g + ((cip * 4 + a) * 16 + co) * 4);
                    const u32 wv[4] = {wq.x, wq.y, wq.z, wq.w};
                    #pragma unroll
                    for (int x = 0; x < 14; ++x) {
                        const int c0v = (x + 1) & 1;
                        const int ix0 = (x + 1 - c0v) >> 1;
                        if (ix0 < 7)  acc[x] = dot2(rr[ix0],     wv[c0v],     acc[x]);
                        if (ix0 >= 1) acc[x] = dot2(rr[ix0 - 1], wv[c0v + 2], acc[x]);
                    }
                }
            }
        }
        u16* dst = (u16*)&c1s[co >> 1][y][0] + (co & 1);
        #pragma unroll
        for (int x = 0; x < 14; ++x) dst[2 * x] = f16b(lrelu(acc[x]));
    }
    __syncthreads();   // h2s dead; c2s may be written

    // conv2: [16,14,14] -> [8,28,28]
    if (tid < 224) {
        const int co = tid / 28, y = tid % 28;
        const float bv = cb2g[co];
        u16* dst = (u16*)&c2s[co >> 1][y][0] + (co & 1);
        conv2p_half<0>(c1s, dst, w2g, bv, co, y);
        conv2p_half<1>(c1s, dst, w2g, bv, co, y);
    }
    __syncthreads();

    // conv3: [8,28,28] -> [1,28,28], k=3 s=1, ci-pairs via dot2
    if (tid < 196) {
        const int y = tid / 7, qq = tid % 7;
        const int xb = qq * 4;
        float acc[4] = {cb3v, cb3v, cb3v, cb3v};
        #pragma unroll 2
        for (int cip = 0; cip < 4; ++cip) {
            u32 wp[9];
            #pragma unroll
            for (int j = 0; j < 9; ++j) wp[j] = w3s[cip * 9 + j];
            #pragma unroll
            for (int a = 0; a < 3; ++a) {
                const int iy = y + 1 - a;
                if ((unsigned)iy < 28u) {
                    u32 rr[6];
                    #pragma unroll
                    for (int j = 0; j < 6; ++j) {
                        const int ix = xb - 1 + j;
                        rr[j] = ((unsigned)ix < 28u) ? c2s[cip][iy][ix] : 0u;
                    }
                    #pragma unroll
                    for (int xx = 0; xx < 4; ++xx)
                        #pragma unroll
                        for (int c = 0; c < 3; ++c)
                            acc[xx] = dot2(rr[xx + 2 - c], wp[a * 3 + c], acc[xx]);
                }
            }
        }
        float* op = out + (size_t)b * 784 + y * 28 + xb;
        #pragma unroll
        for (int xx = 0; xx < 4; ++xx) op[xx] = fast_tanh(acc[xx]);
    }
}

extern "C" void kernel_launch(void* const* d_in, const int* in_sizes, int n_in,
                              void* d_out, int out_size, void* d_ws, size_t ws_size,
                              hipStream_t stream) {
    const float* z   = (const float*)d_in[0];
    const int*   gi  = (const int*)d_in[1];
    const float* W1  = (const float*)d_in[2];
    const float* b1  = (const float*)d_in[3];
    const float* W2  = (const float*)d_in[4];
    const float* b2  = (const float*)d_in[5];
    const float* cw1 = (const float*)d_in[6];
    const float* cb1 = (const float*)d_in[7];
    const float* cw2 = (const float*)d_in[8];
    const float* cb2 = (const float*)d_in[9];
    const float* cw3 = (const float*)d_in[10];
    const float* cb3 = (const float*)d_in[11];
    int*      wsi = (int*)d_ws;
    float*    h1g = (float*)((char*)d_ws + WS_H1_OFF);
    u16*      h2g = (u16*)((char*)d_ws + WS_H2_OFF);
    _Float16* w2t = (_Float16*)((char*)d_ws + WS_W2T_OFF);
    u32*      wpk1 = (u32*)((char*)d_ws + WS_WPK1_OFF);
    u32*      wpk2 = (u32*)((char*)d_ws + WS_WPK2_OFF);
    u32*      wpk3 = (u32*)((char*)d_ws + WS_WPK3_OFF);

    bin_kernel<<<1, 256, 0, stream>>>(gi, wsi);
    prep_kernel<<<NB_PREP + NGEN, 256, 0, stream>>>(z, gi, W1, b1, W2, wsi, h1g, w2t,
                                                    cw1, cw2, cw3, wpk1, wpk2, wpk3);
    fc2_kernel<<<MAXG * NCT, 256, 0, stream>>>(gi, w2t, b2, wsi, h1g, h2g);
    conv_kernel<<<BATCH, 256, 0, stream>>>(gi, wpk1, cb1, wpk2, cb2, wpk3, cb3,
                                           h2g, (float*)d_out);
}

// Round 3
// 161.164 us; speedup vs baseline: 1.2356x; 1.0326x over previous
//
#include <hip/hip_runtime.h>
#include <cstdint>
#include <cstddef>

#define BATCH 2048
#define NZ 128
#define NGEN 8
#define GRPS 32                 // samples per group (same generator)
#define MAXG 72                 // max padded groups
#define NCT 13                  // fc2 col tiles of 128 (12 full + tail 32)
#define H2_ELEMS 1792           // 32*7*8 (x padded 7->8) per sample, f16
#define WS_H1_OFF 16384                                  // h1: 72*8192 fp32
#define WS_H2_OFF (16384 + MAXG * 8192 * 4)              // 2375680
#define WS_W2T_OFF (WS_H2_OFF + BATCH * H2_ELEMS * 2)    // 9715712
#define W2T_GSTRIDE (1568 * 256)                         // fp16 elems per gen
#define NB_W2T (NGEN * 49)                               // 392
#define NB_PREP (NB_W2T + MAXG * 4)                      // 680
// packed f16x2 conv weights (pairs over input channel), per generator:
//   wpk1[g][cip16][a4][co16][c4], wpk2[g][cip8][a4][co8][c4], wpk3[g][cip4][9]
#define WS_WPK1_OFF (WS_W2T_OFF + NGEN * W2T_GSTRIDE * 2)  // 16138240 (16B aligned)
#define WS_WPK2_OFF (WS_WPK1_OFF + NGEN * 4096 * 4)
#define WS_WPK3_OFF (WS_WPK2_OFF + NGEN * 1024 * 4)
#define PS 168                  // fc2 epilogue LDS row stride (u16), 336B = 16B-mult

typedef unsigned int u32;
typedef unsigned short u16;
typedef unsigned long long u64;
typedef _Float16 f16x8 __attribute__((ext_vector_type(8)));
typedef _Float16 f16x4 __attribute__((ext_vector_type(4)));
typedef _Float16 f16x2 __attribute__((ext_vector_type(2)));
typedef float f32x4 __attribute__((ext_vector_type(4)));

__device__ __forceinline__ float lrelu(float x) { return fmaxf(x, 0.2f * x); }
__device__ __forceinline__ u16 f16b(float f) {
    _Float16 h = (_Float16)f;
    return __builtin_bit_cast(u16, h);
}
__device__ __forceinline__ u32 pk2(float a, float b) {
    f16x2 v; v[0] = (_Float16)a; v[1] = (_Float16)b;
    return __builtin_bit_cast(u32, v);
}
// 2-wide f16 dot with f32 accumulate: v_dot2_f32_f16 (2 MACs/instr, full rate)
__device__ __forceinline__ float dot2(u32 a, u32 b, float c) {
#if __has_builtin(__builtin_amdgcn_fdot2)
    return __builtin_amdgcn_fdot2(__builtin_bit_cast(f16x2, a),
                                  __builtin_bit_cast(f16x2, b), c, false);
#else
    float d;
    asm("v_dot2_f32_f16 %0, %1, %2, %3" : "=v"(d) : "v"(a), "v"(b), "v"(c));
    return d;
#endif
}
__device__ __forceinline__ float fast_tanh(float x) {
    x = fminf(fmaxf(x, -9.f), 9.f);
    const float e = __expf(2.f * x);
    return (e - 1.f) / (e + 1.f);
}
// h2 storage offset for fc2 column n (strictly monotone in n)
__device__ __forceinline__ int h2off(int n) {
    const int ci = n / 49, rm = n % 49;
    return ci * 56 + (rm / 7) * 8 + (rm % 7);
}

// ---------------------------------------------------------------------------
// Kernel 1: bin samples by generator — ballot-rank form (no LDS atomics).
// wsi[0] = padded total; wsi[16..] = ids grouped, groups padded to 32 w/ -1.
// ---------------------------------------------------------------------------
__global__ void bin_kernel(const int* __restrict__ g_idx, int* __restrict__ wsi) {
    __shared__ int wcnt[4][NGEN];      // per-wave per-gen counts
    __shared__ int wboff[4][NGEN];     // per-wave base offset inside gen region
    __shared__ int pbase[NGEN + 1];
    __shared__ u16 rank[BATCH];        // wave-local rank within gen
    const int tid = threadIdx.x;
    const int w = tid >> 6, lane = tid & 63;
    if (tid < 4 * NGEN) wcnt[tid >> 3][tid & 7] = 0;
    __syncthreads();
    const u64 lt = ((u64)1 << lane) - 1;
    #pragma unroll
    for (int r = 0; r < 8; ++r) {
        const int b = r * 256 + tid;
        const int gg = g_idx[b];
        u64 m[NGEN];
        #pragma unroll
        for (int k = 0; k < NGEN; ++k) m[k] = __ballot(gg == k);
        rank[b] = (u16)((int)__popcll(m[gg] & lt) + wcnt[w][gg]);
        if (lane < NGEN) wcnt[w][lane] += (int)__popcll(m[lane]);
    }
    __syncthreads();
    if (tid == 0) {
        int acc = 0;
        for (int g = 0; g < NGEN; ++g) {
            pbase[g] = acc;
            const int tot = wcnt[0][g] + wcnt[1][g] + wcnt[2][g] + wcnt[3][g];
            acc += ((tot + GRPS - 1) / GRPS) * GRPS;
        }
        pbase[NGEN] = acc;
        wsi[0] = acc;
    }
    __syncthreads();
    if (tid < 32) {
        const int ww = tid >> 3, g = tid & 7;
        int off = pbase[g];
        for (int w2 = 0; w2 < ww; ++w2) off += wcnt[w2][g];
        wboff[ww][g] = off;
    }
    const int total = pbase[NGEN];
    for (int i = tid; i < total; i += 256) wsi[16 + i] = -1;
    __syncthreads();
    #pragma unroll
    for (int r = 0; r < 8; ++r) {
        const int b = r * 256 + tid;
        const int gg = g_idx[b];
        wsi[16 + wboff[w][gg] + (int)rank[b]] = b;
    }
}

// ---------------------------------------------------------------------------
// Kernel 2: prep = W2 transpose (blocks 0..391) + grouped FC1 (392..679)
//           + conv-weight f16x2 packing (blocks 680..687, one per generator).
// W2T copy-out uses flat chunk mapping: consecutive lanes -> consecutive 16B
// chunks -> each wave writes 1KB fully contiguous (was 16B pieces @64B stride).
// ---------------------------------------------------------------------------
__global__ __launch_bounds__(256) void prep_kernel(
    const float* __restrict__ z, const int* __restrict__ g_idx,
    const float* __restrict__ W1, const float* __restrict__ b1,
    const float* __restrict__ W2, const int* __restrict__ wsi,
    float* __restrict__ h1g, _Float16* __restrict__ W2T,
    const float* __restrict__ cw1, const float* __restrict__ cw2,
    const float* __restrict__ cw3,
    u32* __restrict__ wpk1, u32* __restrict__ wpk2, u32* __restrict__ wpk3)
{
    __shared__ _Float16 t[32][264];   // w2t role, 16.5 KB
    __shared__ float zst[NZ][12];     // fc1 role, 6 KB
    __shared__ int sb[8];
    __shared__ int sG;

    const int tid = threadIdx.x;
    const int bx = blockIdx.x;

    if (bx >= NB_PREP) {
        // ---- conv-weight packing role: pair input channels into f16x2 ----
        const int g = bx - NB_PREP;
        const float* c1p = cw1 + g * 8192;             // [32ci][16co][4][4]
        u32* o1 = wpk1 + g * 4096;
        for (int i = tid; i < 4096; i += 256) {
            const int cip = i >> 8, a = (i >> 6) & 3, co = (i >> 2) & 15, c = i & 3;
            const float* s = c1p + cip * 512 + co * 16 + a * 4 + c;
            o1[i] = pk2(s[0], s[256]);
        }
        const float* c2p = cw2 + g * 2048;             // [16ci][8co][4][4]
        u32* o2 = wpk2 + g * 1024;
        for (int i = tid; i < 1024; i += 256) {
            const int cip = i >> 7, a = (i >> 5) & 3, co = (i >> 2) & 7, c = i & 3;
            const float* s = c2p + cip * 256 + co * 16 + a * 4 + c;
            o2[i] = pk2(s[0], s[128]);
        }
        if (tid < 36) {                                // [8ci][1co][3][3]
            const int cip = tid / 9, r = tid % 9;
            const float* s = cw3 + g * 72 + cip * 18 + r;
            wpk3[g * 36 + tid] = pk2(s[0], s[9]);
        }
        return;
    }

    if (bx < NB_W2T) {
        // ---- W2 transpose role: W2[g][k256][n1568] fp32 -> W2T[g][n][k] fp16
        const int g = bx / 49;
        const int n0 = (bx % 49) * 32;
        const float* src = W2 + (size_t)g * 256 * 1568;
        const int nl = tid & 31, kh = tid >> 5;
        #pragma unroll 8
        for (int p = 0; p < 32; ++p) {
            const int k = p * 8 + kh;
            t[nl][k] = (_Float16)src[(size_t)k * 1568 + n0 + nl];
        }
        __syncthreads();
        _Float16* dst = W2T + (size_t)g * W2T_GSTRIDE + (size_t)n0 * 256;
        #pragma unroll
        for (int ii = 0; ii < 4; ++ii) {
            const int i = tid + 256 * ii;           // 1024 chunks of 16B
            const int n = i >> 5, kc = i & 31;
            *(uint4*)(dst + (size_t)n * 256 + kc * 8) = *(const uint4*)&t[n][kc * 8];
        }
        return;
    }

    // ---- FC1 role (grouped): (group, 8-sample slice) ----
    const int bx2 = bx - NB_W2T;
    const int grp = bx2 >> 2;
    const int s0 = (bx2 & 3) * 8;
    if (grp * GRPS >= wsi[0]) return;

    if (tid == 0) sG = g_idx[wsi[16 + grp * GRPS]];
    if (tid < 8) sb[tid] = wsi[16 + grp * GRPS + s0 + tid];
    __syncthreads();
    const float* W1g = W1 + sG * (NZ * 256);
    const float* b1g = b1 + sG * 256;

    {   // stage z: 8 samples x 128 = 256 float4, one per thread
        const int s = tid >> 5, f = tid & 31;
        float4 v = make_float4(0.f, 0.f, 0.f, 0.f);
        if (sb[s] >= 0) v = *(const float4*)(z + (size_t)sb[s] * NZ + 4 * f);
        zst[4 * f + 0][s] = v.x; zst[4 * f + 1][s] = v.y;
        zst[4 * f + 2][s] = v.z; zst[4 * f + 3][s] = v.w;
    }
    __syncthreads();

    const int c = tid;
    float acc[8];
    #pragma unroll
    for (int s = 0; s < 8; ++s) acc[s] = 0.f;
    const float* wp = W1g + c;
    #pragma unroll 4
    for (int k = 0; k < NZ; ++k) {
        const float w = wp[k * 256];
        float av[8];
        *(float4*)&av[0] = *(const float4*)&zst[k][0];
        *(float4*)&av[4] = *(const float4*)&zst[k][4];
        #pragma unroll
        for (int s = 0; s < 8; ++s) acc[s] += av[s] * w;
    }
    const float bv = b1g[c];
    float* hp = h1g + (size_t)grp * 8192 + (size_t)s0 * 256 + c;
    #pragma unroll
    for (int s = 0; s < 8; ++s) hp[s * 256] = lrelu(acc[s] + bv);
}

// ---------------------------------------------------------------------------
// Kernel 3: FC2 via fp16 MFMA 16x16x32, single-f16 A.
// NEW: coalesced epilogue. off(n) is strictly monotone, so this block's 128
// n-cols map to one contiguous off-range (span<=147). Stage P into pst[32][PS]
// u16 (reusing dead afrag LDS), then write h2g rows as aligned 16B chunks with
// exact head/tail ownership (offs in [offLo,offHi] only -> no cross-tile
// clobber; pad offs inside the range are never read by conv).
// ---------------------------------------------------------------------------
__global__ __launch_bounds__(256) void fc2_kernel(
    const int* __restrict__ g_idx,
    const _Float16* __restrict__ W2T, const float* __restrict__ b2,
    const int* __restrict__ wsi, const float* __restrict__ h1g,
    u16* __restrict__ h2g)
{
    __shared__ __align__(16) char afsm[16384];   // afrag 16KB, then pst 32*PS*2
    _Float16* afrag = (_Float16*)afsm;
    __shared__ int sb[GRPS];
    __shared__ int sG;

    const int tid = threadIdx.x;
    const int grp = blockIdx.x / NCT;
    const int tile = blockIdx.x % NCT;
    if (grp * GRPS >= wsi[0]) return;   // whole block uniform: before barriers

    if (tid == 0) sG = g_idx[wsi[16 + grp * GRPS]];
    if (tid < GRPS) sb[tid] = wsi[16 + grp * GRPS + tid];
    __syncthreads();
    const _Float16* W2Tg = W2T + (size_t)sG * W2T_GSTRIDE;
    const float* b2g = b2 + sG * 1568;

    // ---- stage A fragments (single f16), conflict-free stores ----
    {
        const float4* h1p4 = (const float4*)(h1g + (size_t)grp * 8192);
        #pragma unroll
        for (int i = 0; i < 8; ++i) {
            const int u = tid + 256 * i;
            const int j4 = u & 1;                  // j base = 4*j4
            const int ln = (u >> 1) & 63;
            const int kq = (u >> 7) & 7;
            const int mt = (u >> 10) & 1;
            const int s = mt * 16 + (ln & 15);
            const float4 v = h1p4[s * 64 + kq * 8 + ((ln >> 4) << 1) + j4];
            f16x4 hi;
            hi[0] = (_Float16)v.x; hi[1] = (_Float16)v.y;
            hi[2] = (_Float16)v.z; hi[3] = (_Float16)v.w;
            const int bh = ((mt * 8 + kq) * 64 + ln) * 8 + 4 * j4;
            *(f16x4*)&afrag[bh] = hi;   // addr = base + 8*u bytes: conflict-free
        }
    }
    __syncthreads();

    const int wave = tid >> 6;
    const int lane = tid & 63;
    const int q = lane >> 4;
    const int nl = lane & 15;
    const int nb0 = tile * 128 + 2 * wave * 16;
    const int nb1 = nb0 + 16;
    const bool act0 = nb0 < 1568, act1 = nb1 < 1568;

    f32x4 accA0 = {0.f, 0.f, 0.f, 0.f}, accB0 = accA0;
    f32x4 accA1 = accA0, accB1 = accA0;
    if (act0) {
        const _Float16* bp = W2Tg + (size_t)(nb0 + nl) * 256 + q * 8;
        #pragma unroll
        for (int kq = 0; kq < 8; ++kq) {
            const f16x8 b = *(const f16x8*)(bp + kq * 32);
            const f16x8 a0 = *(const f16x8*)&afrag[((0 * 8 + kq) * 64 + lane) * 8];
            const f16x8 a1 = *(const f16x8*)&afrag[((1 * 8 + kq) * 64 + lane) * 8];
            accA0 = __builtin_amdgcn_mfma_f32_16x16x32_f16(a0, b, accA0, 0, 0, 0);
            accB0 = __builtin_amdgcn_mfma_f32_16x16x32_f16(a1, b, accB0, 0, 0, 0);
        }
    }
    if (act1) {
        const _Float16* bp = W2Tg + (size_t)(nb1 + nl) * 256 + q * 8;
        #pragma unroll
        for (int kq = 0; kq < 8; ++kq) {
            const f16x8 b = *(const f16x8*)(bp + kq * 32);
            const f16x8 a0 = *(const f16x8*)&afrag[((0 * 8 + kq) * 64 + lane) * 8];
            const f16x8 a1 = *(const f16x8*)&afrag[((1 * 8 + kq) * 64 + lane) * 8];
            accA1 = __builtin_amdgcn_mfma_f32_16x16x32_f16(a0, b, accA1, 0, 0, 0);
            accB1 = __builtin_amdgcn_mfma_f32_16x16x32_f16(a1, b, accB1, 0, 0, 0);
        }
    }
    __syncthreads();               // all afrag reads done; reuse as pst

    u16* pst = (u16*)afsm;
    const int nstart = tile * 128;
    const int nend = (nstart + 128 < 1568) ? nstart + 128 : 1568;
    const int offLo = h2off(nstart), offHi = h2off(nend - 1);
    const int lo8 = offLo & ~7;

    if (act0) {
        const int n = nb0 + nl;
        const float bias = b2g[n];
        u16* pp = pst + (h2off(n) - lo8);
        #pragma unroll
        for (int reg = 0; reg < 4; ++reg) {
            pp[(q * 4 + reg) * PS]        = f16b(lrelu(accA0[reg] + bias));
            pp[(16 + q * 4 + reg) * PS]   = f16b(lrelu(accB0[reg] + bias));
        }
    }
    if (act1) {
        const int n = nb1 + nl;
        const float bias = b2g[n];
        u16* pp = pst + (h2off(n) - lo8);
        #pragma unroll
        for (int reg = 0; reg < 4; ++reg) {
            pp[(q * 4 + reg) * PS]        = f16b(lrelu(accA1[reg] + bias));
            pp[(16 + q * 4 + reg) * PS]   = f16b(lrelu(accB1[reg] + bias));
        }
    }
    __syncthreads();

    // ---- coalesced copy-out: 8 threads per sample ----
    {
        const int s = tid >> 3, p = tid & 7;
        const int bb = sb[s];
        if (bb >= 0) {
            u16* row = h2g + (size_t)bb * H2_ELEMS;
            const u16* ps = pst + s * PS - lo8;        // index by off directly
            const int c0 = (offLo + 7) & ~7;           // first aligned chunk
            const int c1 = (offHi + 1) & ~7;           // end of aligned chunks
            for (int o = offLo + p; o < c0 && o <= offHi; o += 8) row[o] = ps[o];
            const int t0 = (c1 > offLo) ? c1 : offLo;
            for (int o = t0 + p; o <= offHi; o += 8) row[o] = ps[o];
            for (int c = c0 + p * 8; c + 8 <= c1; c += 64)
                *(uint4*)(row + c) = *(const uint4*)(ps + c);
        }
    }
}

// ---------------------------------------------------------------------------
// conv2 half-pass, f16x2-pair form (r1-proven config restored).
// ---------------------------------------------------------------------------
template <int H>
__device__ __forceinline__ void conv2p_half(
    const u32 (*c1s)[14][20], u16* dst,
    const u32* __restrict__ w2g, const float bv, const int co, const int y)
{
    float acc[14];
    #pragma unroll
    for (int xx = 0; xx < 14; ++xx) acc[xx] = bv;
    const int a0 = (y + 1) & 1;
    for (int aa = 0; aa < 2; ++aa) {
        const int a = a0 + 2 * aa;
        const int iy = (y + 1 - a) >> 1;
        if ((unsigned)iy < 14u) {
            #pragma unroll 2
            for (int cip = 0; cip < 8; ++cip) {
                u32 rr[10];                         // H0: ix 0..7; H1: ix 4..13
                if (H == 0) {
                    *(uint4*)&rr[0] = *(const uint4*)&c1s[cip][iy][0];
                    *(uint4*)&rr[4] = *(const uint4*)&c1s[cip][iy][4];
                } else {
                    *(uint4*)&rr[0] = *(const uint4*)&c1s[cip][iy][4];
                    *(uint4*)&rr[4] = *(const uint4*)&c1s[cip][iy][8];
                    *(uint2*)&rr[8] = *(const uint2*)&c1s[cip][iy][12];
                }
                const uint4 wq = *(const uint4*)(w2g + ((cip * 4 + a) * 8 + co) * 4);
                const u32 wv[4] = {wq.x, wq.y, wq.z, wq.w};
                #pragma unroll
                for (int xx = 0; xx < 14; ++xx) {
                    const int x = 14 * H + xx;
                    const int c0v = (x + 1) & 1;
                    const int ix0 = (x + 1 - c0v) >> 1;
                    const int li = ix0 - 4 * H;
                    if (ix0 < 14) acc[xx] = dot2(rr[li],     wv[c0v],     acc[xx]);
                    if (ix0 >= 1) acc[xx] = dot2(rr[li - 1], wv[c0v + 2], acc[xx]);
                }
            }
        }
    }
    #pragma unroll
    for (int xx = 0; xx < 14; ++xx) dst[2 * (14 * H + xx)] = f16b(lrelu(acc[xx]));
}

// ---------------------------------------------------------------------------
// Kernel 4: all three transposed convs, ONE sample per block.
// EXACT round-1 proven config (c2s stride 33, bounds(256,6)): 48.5 us measured.
// ---------------------------------------------------------------------------
__global__ __launch_bounds__(256, 6) void conv_kernel(
    const int* __restrict__ g_idx,
    const u32* __restrict__ wpk1, const float* __restrict__ cb1,
    const u32* __restrict__ wpk2, const float* __restrict__ cb2,
    const u32* __restrict__ wpk3, const float* __restrict__ cb3,
    const u16* __restrict__ h2g, float* __restrict__ out)
{
    __shared__ __align__(16) char smem[8960 + 14784];
    u32 (*c1s)[14][20] = (u32 (*)[14][20])smem;              // [8cip][14][20] 8960 B
    u32 (*h2s)[7][8]   = (u32 (*)[7][8])(smem + 8960);       // [16cip][7][8] 3584 B
    u32 (*c2s)[28][33] = (u32 (*)[28][33])(smem + 8960);     // [4cip][28][33] aliases h2s
    __shared__ u32 w3s[36];

    const int tid = threadIdx.x;
    const int b = blockIdx.x;
    const int g = g_idx[b];
    const u32* w1g = wpk1 + g * 4096;
    const u32* w2g = wpk2 + g * 1024;
    const float* cb1g = cb1 + g * 16;
    const float* cb2g = cb2 + g * 8;
    const float  cb3v = cb3[g];

    // stage h2 (f16 bits straight from fc2) into ci-paired layout
    if (tid < 224) {
        const uint4 qv = ((const uint4*)(h2g + (size_t)b * H2_ELEMS))[tid];
        const int ci = tid / 7, yq = tid % 7;
        u16* dst = (u16*)&h2s[ci >> 1][yq][0] + (ci & 1);
        const u32 w[4] = {qv.x, qv.y, qv.z, qv.w};
        #pragma unroll
        for (int j = 0; j < 4; ++j) {
            dst[4 * j]     = (u16)(w[j] & 0xffffu);
            dst[4 * j + 2] = (u16)(w[j] >> 16);
        }
    }
    if (tid < 36) w3s[tid] = wpk3[g * 36 + tid];
    __syncthreads();

    // conv1: [32,7,7] -> [16,14,14], k=4, s=2, ci-pairs via dot2
    if (tid < 224) {
        const int co = tid / 14, y = tid % 14;
        const float bv = cb1g[co];
        float acc[14];
        #pragma unroll
        for (int x = 0; x < 14; ++x) acc[x] = bv;
        const int a0 = (y + 1) & 1;
        for (int aa = 0; aa < 2; ++aa) {
            const int a = a0 + 2 * aa;
            const int iy = (y + 1 - a) >> 1;
            if ((unsigned)iy < 7u) {
                #pragma unroll 2
                for (int cip = 0; cip < 16; ++cip) {
                    u32 rr[8];
                    *(uint4*)&rr[0] = *(const uint4*)&h2s[cip][iy][0];
                    *(uint4*)&rr[4] = *(const uint4*)&h2s[cip][iy][4];
                    const uint4 wq = *(const uint4*)(w1g + ((cip * 4 + a) * 16 + co) * 4);
                    const u32 wv[4] = {wq.x, wq.y, wq.z, wq.w};
                    #pragma unroll
                    for (int x = 0; x < 14; ++x) {
                        const int c0v = (x + 1) & 1;
                        const int ix0 = (x + 1 - c0v) >> 1;
                        if (ix0 < 7)  acc[x] = dot2(rr[ix0],     wv[c0v],     acc[x]);
                        if (ix0 >= 1) acc[x] = dot2(rr[ix0 - 1], wv[c0v + 2], acc[x]);
                    }
                }
            }
        }
        u16* dst = (u16*)&c1s[co >> 1][y][0] + (co & 1);
        #pragma unroll
        for (int x = 0; x < 14; ++x) dst[2 * x] = f16b(lrelu(acc[x]));
    }
    __syncthreads();   // h2s dead; c2s may be written

    // conv2: [16,14,14] -> [8,28,28]
    if (tid < 224) {
        const int co = tid / 28, y = tid % 28;
        const float bv = cb2g[co];
        u16* dst = (u16*)&c2s[co >> 1][y][0] + (co & 1);
        conv2p_half<0>(c1s, dst, w2g, bv, co, y);
        conv2p_half<1>(c1s, dst, w2g, bv, co, y);
    }
    __syncthreads();

    // conv3: [8,28,28] -> [1,28,28], k=3 s=1, ci-pairs via dot2
    if (tid < 196) {
        const int y = tid / 7, qq = tid % 7;
        const int xb = qq * 4;
        float acc[4] = {cb3v, cb3v, cb3v, cb3v};
        #pragma unroll 2
        for (int cip = 0; cip < 4; ++cip) {
            u32 wp[9];
            #pragma unroll
            for (int j = 0; j < 9; ++j) wp[j] = w3s[cip * 9 + j];
            #pragma unroll
            for (int a = 0; a < 3; ++a) {
                const int iy = y + 1 - a;
                if ((unsigned)iy < 28u) {
                    u32 rr[6];
                    #pragma unroll
                    for (int j = 0; j < 6; ++j) {
                        const int ix = xb - 1 + j;
                        rr[j] = ((unsigned)ix < 28u) ? c2s[cip][iy][ix] : 0u;
                    }
                    #pragma unroll
                    for (int xx = 0; xx < 4; ++xx)
                        #pragma unroll
                        for (int c = 0; c < 3; ++c)
                            acc[xx] = dot2(rr[xx + 2 - c], wp[a * 3 + c], acc[xx]);
                }
            }
        }
        float* op = out + (size_t)b * 784 + y * 28 + xb;
        #pragma unroll
        for (int xx = 0; xx < 4; ++xx) op[xx] = fast_tanh(acc[xx]);
    }
}

extern "C" void kernel_launch(void* const* d_in, const int* in_sizes, int n_in,
                              void* d_out, int out_size, void* d_ws, size_t ws_size,
                              hipStream_t stream) {
    const float* z   = (const float*)d_in[0];
    const int*   gi  = (const int*)d_in[1];
    const float* W1  = (const float*)d_in[2];
    const float* b1  = (const float*)d_in[3];
    const float* W2  = (const float*)d_in[4];
    const float* b2  = (const float*)d_in[5];
    const float* cw1 = (const float*)d_in[6];
    const float* cb1 = (const float*)d_in[7];
    const float* cw2 = (const float*)d_in[8];
    const float* cb2 = (const float*)d_in[9];
    const float* cw3 = (const float*)d_in[10];
    const float* cb3 = (const float*)d_in[11];
    int*      wsi = (int*)d_ws;
    float*    h1g = (float*)((char*)d_ws + WS_H1_OFF);
    u16*      h2g = (u16*)((char*)d_ws + WS_H2_OFF);
    _Float16* w2t = (_Float16*)((char*)d_ws + WS_W2T_OFF);
    u32*      wpk1 = (u32*)((char*)d_ws + WS_WPK1_OFF);
    u32*      wpk2 = (u32*)((char*)d_ws + WS_WPK2_OFF);
    u32*      wpk3 = (u32*)((char*)d_ws + WS_WPK3_OFF);

    bin_kernel<<<1, 256, 0, stream>>>(gi, wsi);
    prep_kernel<<<NB_PREP + NGEN, 256, 0, stream>>>(z, gi, W1, b1, W2, wsi, h1g, w2t,
                                                    cw1, cw2, cw3, wpk1, wpk2, wpk3);
    fc2_kernel<<<MAXG * NCT, 256, 0, stream>>>(gi, w2t, b2, wsi, h1g, h2g);
    conv_kernel<<<BATCH, 256, 0, stream>>>(gi, wpk1, cb1, wpk2, cb2, wpk3, cb3,
                                           h2g, (float*)d_out);
}